// Round 7
// baseline (564.324 us; speedup 1.0000x reference)
//
#include <hip/hip_runtime.h>
#include <hip/hip_bf16.h>

// ConvTranspose4d: B=2, CIN=32, COUT=32, S=16^4, K=3^4, pad=0, stride=1
// y[b,co,o] = bias[co] + sum_{ci, k in [0,3)^4, 0<=o-k<16} x[b,ci,o-k] * w[ci,co,k]
// out spatial = 18^4.
//
// Block = (b,o0,o1), 648 blocks x 576 threads (9 full waves).
// Thread = (co-pair t&15, o2 = (t>>4)>>1, h = (t>>4)&1).
// Thread accumulates y[o3] for o3 = 8h + (m+k3), m in [0,8): i3 = 8h+m.
// Halves overlap at o3 in {8,9}; combined via LDS at epilogue.

#define B_    2
#define CIN_  32
#define SD    16
#define OD    18
#define NTAP  81
#define CHUNK 4
#define THREADS 576

// LPT block ordering: decode r in [0,324) -> (o0,o1), heaviest class first.
// classes by n0*n1: 9 (196 pairs), 6 (56), 4 (4), 3 (56), 2 (8), 1 (4).
__device__ inline void decode_o01(int r, int& o0, int& o1) {
    if (r < 196) {                      // [2,15] x [2,15]
        o0 = 2 + r / 14; o1 = 2 + r % 14;
    } else if (r < 252) {               // cost 6
        int q = r - 196;
        if (q < 28) { o0 = 2 + (q >> 1); o1 = (q & 1) ? 16 : 1; }
        else { q -= 28;  o1 = 2 + (q >> 1); o0 = (q & 1) ? 16 : 1; }
    } else if (r < 256) {               // cost 4: {1,16}^2
        int q = r - 252;
        o0 = (q & 1) ? 16 : 1; o1 = (q >> 1) ? 16 : 1;
    } else if (r < 312) {               // cost 3
        int q = r - 256;
        if (q < 28) { o0 = 2 + (q >> 1); o1 = (q & 1) ? 17 : 0; }
        else { q -= 28;  o1 = 2 + (q >> 1); o0 = (q & 1) ? 17 : 0; }
    } else if (r < 320) {               // cost 2
        int q = r - 312;
        if (q < 4) { o0 = (q & 1) ? 16 : 1; o1 = (q >> 1) ? 17 : 0; }
        else { q -= 4; o0 = (q & 1) ? 17 : 0; o1 = (q >> 1) ? 16 : 1; }
    } else {                            // cost 1: {0,17}^2
        int q = r - 320;
        o0 = (q & 1) ? 17 : 0; o1 = (q >> 1) ? 17 : 0;
    }
}

__global__ __launch_bounds__(THREADS, 5)
void convt4d_kernel(const float* __restrict__ x,
                    const float* __restrict__ w,
                    const float* __restrict__ bias,
                    float* __restrict__ y) {
    const int bid = blockIdx.x;          // 0..647
    const int b   = bid & 1;
    int o0, o1;
    decode_o01(bid >> 1, o0, o1);

    const int t   = threadIdx.x;
    const int co  = t & 15;              // co-pair: owns co and co+16
    const int rr_ = t >> 4;              // 0..35
    const int h   = rr_ & 1;             // o3 half
    const int o2  = rr_ >> 1;            // 0..17
    const int i3b = h * 8;               // i3 base for this half

    // block-uniform valid k0/k1 tap ranges (i = o - k must be in [0,16))
    const int k0lo = max(0, o0 - (SD - 1)), k0hi = min(2, o0);
    const int k1lo = max(0, o1 - (SD - 1)), k1hi = min(2, o1);
    const int n0 = k0hi - k0lo + 1;      // 1..3
    const int n1 = k1hi - k1lo + 1;      // 1..3

    __shared__ float4 xs4[CHUNK][3][3][64];        // 36.9 KB
    __shared__ float  wsl[CHUNK * 32 * NTAP];      // 41.5 KB

    float a0[10], a1[10];
#pragma unroll
    for (int j = 0; j < 10; ++j) { a0[j] = 0.f; a1[j] = 0.f; }

    for (int cc = 0; cc < CIN_; cc += CHUNK) {
        // ---- stage x[b, cc..cc+3, i0(valid), i1(valid), :, :] into LDS ----
        {
            const int total4 = CHUNK * n0 * n1 * 64;     // <= 2304 float4
            for (int idx = t; idx < total4; idx += THREADS) {
                const int rw = idx >> 6, e = idx & 63;
                const int ci = rw / (n0 * n1);
                const int r2 = rw - ci * (n0 * n1);
                const int s0 = r2 / n1, s1 = r2 - s0 * n1;
                const int i0 = o0 - (k0lo + s0);
                const int i1 = o1 - (k1lo + s1);
                xs4[ci][s0][s1][e] = ((const float4*)(x +
                    ((((size_t)b * CIN_ + (cc + ci)) * SD + i0) * SD + i1) * (SD * SD)))[e];
            }
        }
        // ---- stage w[cc..cc+3, :, all 81 taps] into LDS (contiguous slab) ----
        {
            const float4* src = (const float4*)(w + (size_t)cc * 32 * NTAP);
            float4*       dst = (float4*)wsl;
            for (int idx = t; idx < CHUNK * 32 * NTAP / 4; idx += THREADS)
                dst[idx] = src[idx];
        }
        __syncthreads();

        // ---- compute ----
        for (int ci = 0; ci < CHUNK; ++ci) {
            for (int s0 = 0; s0 < n0; ++s0) {
                for (int s1 = 0; s1 < n1; ++s1) {
                    const int k0 = k0lo + s0, k1 = k1lo + s1;
                    const float* wp0 = &wsl[(ci * 32 + co) * NTAP + (k0 * 3 + k1) * 9];
                    const float* wp1 = wp0 + 16 * NTAP;
                    float wv0[9], wv1[9];
#pragma unroll
                    for (int q = 0; q < 9; ++q) { wv0[q] = wp0[q]; wv1[q] = wp1[q]; }
                    const float* base = (const float*)xs4[ci][s0][s1];
#pragma unroll
                    for (int k2 = 0; k2 < 3; ++k2) {
                        const int i2 = o2 - k2;
                        if ((unsigned)i2 < (unsigned)SD) {
                            const float* xr = base + i2 * SD + i3b;
                            const float4 xa = ((const float4*)xr)[0];
                            const float4 xb = ((const float4*)xr)[1];
                            const float xv[8] = {xa.x, xa.y, xa.z, xa.w,
                                                 xb.x, xb.y, xb.z, xb.w};
#pragma unroll
                            for (int k3 = 0; k3 < 3; ++k3) {
                                const float c0 = wv0[k2 * 3 + k3];
                                const float c1 = wv1[k2 * 3 + k3];
#pragma unroll
                                for (int m = 0; m < 8; ++m) {
                                    a0[m + k3] += c0 * xv[m];   // o3 = 8h + m + k3
                                    a1[m + k3] += c1 * xv[m];
                                }
                            }
                        }
                    }
                }
            }
        }
        __syncthreads();
    }

    // ---- combine overlap (o3 = 8,9) via LDS, then write with bias ----
    float* bnd = (float*)xs4;            // xs dead after final barrier
    const int slot = (o2 * 16 + co) * 4;
    if (h == 0) {
        bnd[slot + 0] = a0[8]; bnd[slot + 1] = a0[9];
        bnd[slot + 2] = a1[8]; bnd[slot + 3] = a1[9];
    }
    __syncthreads();

    const float bb0 = bias[co], bb1 = bias[co + 16];
    float* y0 = y + (((((size_t)b * 32 + co) * OD + o0) * OD + o1) * OD + o2) * OD;
    float* y1 = y0 + (size_t)16 * OD * OD * OD * OD;
    if (h == 0) {
        // o3 = 0..7
#pragma unroll
        for (int j = 0; j < 4; ++j) {
            ((float2*)y0)[j] = make_float2(a0[2 * j] + bb0, a0[2 * j + 1] + bb0);
            ((float2*)y1)[j] = make_float2(a1[2 * j] + bb1, a1[2 * j + 1] + bb1);
        }
    } else {
        // o3 = 8..17 ; slots 0,1 get the h=0 partial for o3=8,9
        a0[0] += bnd[slot + 0]; a0[1] += bnd[slot + 1];
        a1[0] += bnd[slot + 2]; a1[1] += bnd[slot + 3];
#pragma unroll
        for (int j = 0; j < 5; ++j) {
            ((float2*)(y0 + 8))[j] = make_float2(a0[2 * j] + bb0, a0[2 * j + 1] + bb0);
            ((float2*)(y1 + 8))[j] = make_float2(a1[2 * j] + bb1, a1[2 * j + 1] + bb1);
        }
    }
}

extern "C" void kernel_launch(void* const* d_in, const int* in_sizes, int n_in,
                              void* d_out, int out_size, void* d_ws, size_t ws_size,
                              hipStream_t stream) {
    const float* x    = (const float*)d_in[0];
    const float* w    = (const float*)d_in[1];
    const float* bias = (const float*)d_in[2];
    float* y = (float*)d_out;

    const int grid = B_ * OD * OD;   // 648 blocks: (b, o0, o1) LPT-ordered
    convt4d_kernel<<<grid, THREADS, 0, stream>>>(x, w, bias, y);
}